// Round 6
// baseline (514.980 us; speedup 1.0000x reference)
//
#include <hip/hip_runtime.h>
#include <stdint.h>
#include <math.h>

// ---------------- types ----------------
typedef __attribute__((ext_vector_type(4))) float f32x4;
typedef __attribute__((ext_vector_type(8))) short s16x8;   // 8 x bf16 (4 VGPRs)
typedef __attribute__((ext_vector_type(4))) unsigned short u16x4;

__device__ __forceinline__ unsigned short f2b(float x) {
    union { float f; uint32_t u; } v; v.f = x;
    uint32_t r = v.u + 0x7FFFu + ((v.u >> 16) & 1u);   // round-to-nearest-even
    return (unsigned short)(r >> 16);
}
__device__ __forceinline__ float b2f(unsigned short u) {
    union { uint32_t u; float f; } v; v.u = (uint32_t)u << 16;
    return v.f;
}

__device__ __forceinline__ void gload16(const unsigned short* g, unsigned short* l) {
    __builtin_amdgcn_global_load_lds(
        (const __attribute__((address_space(1))) unsigned int*)(const void*)g,
        (__attribute__((address_space(3))) unsigned int*)(void*)l,
        16, 0, 0);
}

// ---------------- fused fp32 -> bf16 cast of the 4 weight tensors ----------------
__global__ __launch_bounds__(256) void cast4_kernel(
        const float* __restrict__ a, int na, const float* __restrict__ b, int nb,
        const float* __restrict__ c, int nc, const float* __restrict__ d, int nd,
        unsigned short* __restrict__ oa, unsigned short* __restrict__ ob,
        unsigned short* __restrict__ oc, unsigned short* __restrict__ od) {
    int i = blockIdx.x * 256 + threadIdx.x;
    const float* src; unsigned short* dst; int off;
    if (i < na)                { src = a; dst = oa; off = i; }
    else if (i < na+nb)        { src = b; dst = ob; off = i - na; }
    else if (i < na+nb+nc)     { src = c; dst = oc; off = i - na - nb; }
    else if (i < na+nb+nc+nd)  { src = d; dst = od; off = i - na - nb - nc; }
    else return;
    f32x4 v = ((const f32x4*)src)[off];
    u16x4 o;
    #pragma unroll
    for (int j = 0; j < 4; ++j) o[j] = f2b(v[j]);
    ((u16x4*)dst)[off] = o;
}

// ---------------- LayerNorm (C=1024), fp32 in -> bf16 out ----------------
__global__ __launch_bounds__(256) void ln_kernel(const float* __restrict__ x,
                                                 const float* __restrict__ w,
                                                 const float* __restrict__ b,
                                                 unsigned short* __restrict__ out) {
    const long row = blockIdx.x;
    const int tid = threadIdx.x;
    f32x4 v = *(const f32x4*)(x + row * 1024 + tid * 4);
    float s  = v[0] + v[1] + v[2] + v[3];
    float sq = v[0]*v[0] + v[1]*v[1] + v[2]*v[2] + v[3]*v[3];
    #pragma unroll
    for (int off = 32; off; off >>= 1) {
        s  += __shfl_xor(s, off);
        sq += __shfl_xor(sq, off);
    }
    __shared__ float red[8];
    if ((tid & 63) == 0) { red[tid >> 6] = s; red[4 + (tid >> 6)] = sq; }
    __syncthreads();
    s  = red[0] + red[1] + red[2] + red[3];
    sq = red[4] + red[5] + red[6] + red[7];
    float mu  = s * (1.0f / 1024.0f);
    float var = sq * (1.0f / 1024.0f) - mu * mu;
    float rs  = rsqrtf(var + 1e-5f);
    f32x4 wv = *(const f32x4*)(w + tid * 4);
    f32x4 bv = *(const f32x4*)(b + tid * 4);
    u16x4 o;
    #pragma unroll
    for (int j = 0; j < 4; ++j) o[j] = f2b((v[j] - mu) * rs * wv[j] + bv[j]);
    *(u16x4*)(out + row * 1024 + tid * 4) = o;
}

// ---------------- psum[row][16] -> invl[row] = 1/sum ----------------
__global__ __launch_bounds__(256) void inv_kernel(const float* __restrict__ psum,
                                                  float* __restrict__ invl) {
    const long r = blockIdx.x * 256 + threadIdx.x;       // 65536 rows
    const float* p = psum + (r << 4);
    f32x4 a = *(const f32x4*)p,       b = *(const f32x4*)(p + 4);
    f32x4 c = *(const f32x4*)(p + 8), d = *(const f32x4*)(p + 12);
    float s = (a[0]+a[1]+a[2]+a[3]) + (b[0]+b[1]+b[2]+b[3])
            + (c[0]+c[1]+c[2]+c[3]) + (d[0]+d[1]+d[2]+d[3]);
    invl[r] = 1.0f / s;
}

// ---------------- PV: barrier-free streaming MFMA ----------------
// E bf16 unnormalized exp; att = E*invl (fp32 write in-loop); y = (E.V)*invl.
// block = 4 waves; wave owns 16 q-rows x 64 d. grid (16 qtiles, 64 bh).
__global__ __launch_bounds__(256)
void pv_kernel(const unsigned short* __restrict__ E,    // [64][1024][1024] bf16
               const unsigned short* __restrict__ Vt,   // [64][64][1024] bf16 (d-major)
               const float* __restrict__ invl,          // [64][1024]
               float* __restrict__ att,                 // [64][1024][1024] fp32
               unsigned short* __restrict__ y) {        // [4096][1024] bf16
    const int tid = threadIdx.x, lane = tid & 63, wid = tid >> 6;
    const int bh = blockIdx.y;
    const int q0 = blockIdx.x * 64 + wid * 16;
    const int fr = lane & 15, fs = lane >> 4;

    const unsigned short* Erow = E + ((long)bh << 20) + ((long)(q0 + fr) << 10) + fs * 8;
    const unsigned short* Vb   = Vt + ((long)bh << 16) + fs * 8;
    float* attRow = att + ((long)bh << 20) + ((long)(q0 + fr) << 10) + fs * 8;
    const float il_a = invl[(bh << 10) + q0 + fr];

    f32x4 acc[4] = {};
    s16x8 a_cur = *(const s16x8*)Erow;
    s16x8 b_cur[4];
    #pragma unroll
    for (int n = 0; n < 4; ++n)
        b_cur[n] = *(const s16x8*)(Vb + (long)(n * 16 + fr) * 1024);

    for (int kt = 0; kt < 32; ++kt) {
        const int k1 = (kt + 1) * 32;
        s16x8 a_nxt = {}; s16x8 b_nxt[4] = {};
        if (kt < 31) {
            a_nxt = *(const s16x8*)(Erow + k1);
            #pragma unroll
            for (int n = 0; n < 4; ++n)
                b_nxt[n] = *(const s16x8*)(Vb + (long)(n * 16 + fr) * 1024 + k1);
        }
        // att write: normalized fp32 from current A fragment
        f32x4 p0, p1;
        #pragma unroll
        for (int j = 0; j < 4; ++j) p0[j] = b2f((unsigned short)a_cur[j]) * il_a;
        #pragma unroll
        for (int j = 0; j < 4; ++j) p1[j] = b2f((unsigned short)a_cur[4 + j]) * il_a;
        *(f32x4*)(attRow + kt * 32)     = p0;
        *(f32x4*)(attRow + kt * 32 + 4) = p1;
        #pragma unroll
        for (int n = 0; n < 4; ++n)
            acc[n] = __builtin_amdgcn_mfma_f32_16x16x32_bf16(a_cur, b_cur[n], acc[n], 0, 0, 0);
        a_cur = a_nxt;
        #pragma unroll
        for (int n = 0; n < 4; ++n) b_cur[n] = b_nxt[n];
    }

    // y scatter: [B,T,C] bf16, scaled by invl of the OUTPUT row
    const int bb = bh >> 4, hh = bh & 15;
    float il_e[4];
    #pragma unroll
    for (int r = 0; r < 4; ++r) il_e[r] = invl[(bh << 10) + q0 + fs * 4 + r];
    #pragma unroll
    for (int n = 0; n < 4; ++n)
        #pragma unroll
        for (int r = 0; r < 4; ++r) {
            const int t = q0 + fs * 4 + r;
            const int c = hh * 64 + n * 16 + fr;
            y[((long)(bb * 1024 + t) << 10) + c] = f2b(acc[n][r] * il_e[r]);
        }
}

// ---------------- GEMM: C[n,m] = sum_k A[n,k] * B[m,k]  (both row-major over K) --------
// EPI: 0=QKV scatter, 1=exp(s+mask)->bf16 E + partial rowsums, 3=bias+resid->f32, 4=bias+GELU->bf16
template <int BM, int BN, int EPI>
__global__ __launch_bounds__(256)
void gemm_bt(const unsigned short* __restrict__ A,
             const unsigned short* __restrict__ Bm,
             int K, int lda, int ldb, int ldc,
             long sAz, long sBz,
             const float* __restrict__ bias,
             const float* __restrict__ resid,
             float* __restrict__ outF,
             unsigned short* __restrict__ outB) {
    constexpr int WM = BM / 2, WN = BN / 2;
    constexpr int FM = WM / 16, FN = WN / 16;
    __shared__ unsigned short ldsA[BM * 32];
    __shared__ unsigned short ldsB[BN * 32];

    const int tid  = threadIdx.x;
    const int lane = tid & 63;
    const int wid  = tid >> 6;
    const int wr   = wid >> 1, wc = wid & 1;
    const int bz   = blockIdx.z;
    const int row0 = blockIdx.x * BM;
    const int col0 = blockIdx.y * BN;

    const unsigned short* Ab = A + (long)bz * sAz + (long)row0 * lda;
    const unsigned short* Bb = Bm + (long)bz * sBz + (long)col0 * ldb;

    f32x4 acc[FM][FN] = {};
    const int fr = lane & 15;
    const int fk = (lane >> 4) * 8;

    for (int k0 = 0; k0 < K; k0 += 32) {
        #pragma unroll
        for (int i = 0; i < BM / 64; ++i) {
            int e = i * 2048 + wid * 512 + lane * 8;
            gload16(Ab + k0 + (long)(e >> 5) * lda + (e & 31),
                    &ldsA[i * 2048 + wid * 512]);
        }
        #pragma unroll
        for (int i = 0; i < BN / 64; ++i) {
            int e = i * 2048 + wid * 512 + lane * 8;
            gload16(Bb + k0 + (long)(e >> 5) * ldb + (e & 31),
                    &ldsB[i * 2048 + wid * 512]);
        }
        asm volatile("s_waitcnt vmcnt(0)" ::: "memory");
        __syncthreads();

        s16x8 af[FM], bfr[FN];
        #pragma unroll
        for (int m = 0; m < FM; ++m)
            af[m] = *(const s16x8*)&ldsA[(wr * WM + m * 16 + fr) * 32 + fk];
        #pragma unroll
        for (int n = 0; n < FN; ++n)
            bfr[n] = *(const s16x8*)&ldsB[(wc * WN + n * 16 + fr) * 32 + fk];
        #pragma unroll
        for (int m = 0; m < FM; ++m)
            #pragma unroll
            for (int n = 0; n < FN; ++n)
                acc[m][n] = __builtin_amdgcn_mfma_f32_16x16x32_bf16(af[m], bfr[n], acc[m][n], 0, 0, 0);
        __syncthreads();
    }

    // epilogue: D mapping col=lane&15, row=(lane>>4)*4+reg  [m89-verified]
    const int cj = lane & 15;
    const int r0 = (lane >> 4) * 4;

    if constexpr (EPI == 1) {
        // exp(s + mask) -> bf16 E, plus per-(block,wave) partial row sums (no atomics)
        #pragma unroll
        for (int m = 0; m < FM; ++m) {
            #pragma unroll
            for (int r = 0; r < 4; ++r) {
                const int grow = row0 + wr * WM + m * 16 + r0 + r;   // q-row in [0,1024)
                float rs = 0.0f;
                #pragma unroll
                for (int n = 0; n < FN; ++n) {
                    const int gcol = col0 + wc * WN + n * 16 + cj;
                    float e = __expf(acc[m][n][r] + resid[((long)grow << 10) + gcol]);
                    rs += e;
                    outB[((long)bz << 20) + ((long)grow << 10) + gcol] = f2b(e);
                }
                rs += __shfl_xor(rs, 1); rs += __shfl_xor(rs, 2);
                rs += __shfl_xor(rs, 4); rs += __shfl_xor(rs, 8);
                if (cj == 0)
                    outF[((((long)bz << 10) + grow) << 4) + blockIdx.y * 2 + wc] = rs;
            }
        }
    } else {
        #pragma unroll
        for (int m = 0; m < FM; ++m) {
            #pragma unroll
            for (int n = 0; n < FN; ++n) {
                #pragma unroll
                for (int r = 0; r < 4; ++r) {
                    const int grow = row0 + wr * WM + m * 16 + r0 + r;
                    const int gcol = col0 + wc * WN + n * 16 + cj;
                    float v = acc[m][n][r];
                    if constexpr (EPI == 0) {
                        // QKV scatter: q*0.125 -> [BH,T,64]; k -> [BH,T,64]; v -> vT [BH,64,T]
                        v += bias[gcol];
                        const int bb = grow >> 10, t = grow & 1023;
                        const int seg = gcol >> 10, mm = gcol & 1023;
                        const int hh = mm >> 6, dd = mm & 63;
                        const long bh = bb * 16 + hh;
                        if (seg == 0)
                            outB[(bh << 16) + (t << 6) + dd] = f2b(v * 0.125f);
                        else if (seg == 1)
                            outB[4194304 + (bh << 16) + (t << 6) + dd] = f2b(v);
                        else
                            outB[8388608 + (bh << 16) + (dd << 10) + t] = f2b(v);
                    } else if constexpr (EPI == 3) {
                        const long idx = ((long)grow << 10) + gcol;   // out row stride 1024
                        outF[idx] = v + bias[gcol] + resid[idx];
                    } else if constexpr (EPI == 4) {
                        float u = v + bias[gcol];
                        float g = 0.5f * u * (1.0f + erff(u * 0.70710678118f));
                        outB[(long)grow * ldc + gcol] = f2b(g);
                    }
                }
            }
        }
    }
}

// ---------------- launch ----------------
extern "C" void kernel_launch(void* const* d_in, const int* in_sizes, int n_in,
                              void* d_out, int out_size, void* d_ws, size_t ws_size,
                              hipStream_t stream) {
    (void)in_sizes; (void)n_in; (void)out_size; (void)ws_size;
    const float* x     = (const float*)d_in[0];
    const float* mask  = (const float*)d_in[1];
    const float* ln1w  = (const float*)d_in[2];
    const float* ln1b  = (const float*)d_in[3];
    const float* wqkv  = (const float*)d_in[4];
    const float* bqkv  = (const float*)d_in[5];
    const float* wo    = (const float*)d_in[6];
    const float* bo    = (const float*)d_in[7];
    const float* ln2w  = (const float*)d_in[8];
    const float* ln2b  = (const float*)d_in[9];
    const float* wfc   = (const float*)d_in[10];
    const float* bfc   = (const float*)d_in[11];
    const float* wproj = (const float*)d_in[12];
    const float* bproj = (const float*)d_in[13];

    float* outx = (float*)d_out;                     // [4096,1024] fp32
    float* att  = (float*)d_out + 4194304;           // [64,1024,1024] fp32

    char* ws = (char*)d_ws;
    unsigned short* h_bf     = (unsigned short*)ws;  ws += (size_t)8  << 20;  // [4096,1024]
    unsigned short* wqkv_bf  = (unsigned short*)ws;  ws += (size_t)6  << 20;  // [3072,1024]
    unsigned short* wo_bf    = (unsigned short*)ws;  ws += (size_t)2  << 20;  // [1024,1024]
    unsigned short* wfc_bf   = (unsigned short*)ws;  ws += (size_t)8  << 20;  // [4096,1024]
    unsigned short* wproj_bf = (unsigned short*)ws;  ws += (size_t)8  << 20;  // [1024,4096]
    unsigned short* q_bf     = (unsigned short*)ws;  ws += (size_t)24 << 20;  // q,k,vT contiguous
    unsigned short* k_bf     = q_bf + 4194304;
    unsigned short* vT_bf    = q_bf + 8388608;
    unsigned short* e_b      = (unsigned short*)ws;  ws += (size_t)128 << 20; // [64,1024,1024] bf16 exp
    unsigned short* y_bf     = (unsigned short*)ws;  ws += (size_t)8  << 20;  // [4096,1024]
    float*          x2       = (float*)ws;           ws += (size_t)16 << 20;  // [4096,1024] f32
    unsigned short* gelu_bf  = (unsigned short*)ws;  ws += (size_t)32 << 20;  // [4096,4096]
    float*          psum     = (float*)ws;           ws += (size_t)4  << 20;  // [64,1024,16] f32
    float*          invl     = (float*)ws;           ws += (size_t)256 << 10; // [64,1024] f32

    // weights -> bf16 (single fused launch)
    cast4_kernel<<<12288, 256, 0, stream>>>(
        wqkv, 786432, wo, 262144, wfc, 1048576, wproj, 1048576,
        wqkv_bf, wo_bf, wfc_bf, wproj_bf);

    // LN1
    ln_kernel<<<4096, 256, 0, stream>>>(x, ln1w, ln1b, h_bf);

    // QKV: [4096,1024] x [3072,1024]^T -> q(scaled)/k/vT scatter
    gemm_bt<128, 128, 0><<<dim3(32, 24, 1), 256, 0, stream>>>(
        h_bf, wqkv_bf, 1024, 1024, 1024, 0, 0, 0,
        bqkv, nullptr, nullptr, q_bf);

    // scores: per (b,h): [1024,64] x [1024,64]^T -> E = exp(s+mask) bf16 + psum
    gemm_bt<128, 128, 1><<<dim3(8, 8, 64), 256, 0, stream>>>(
        q_bf, k_bf, 64, 64, 64, 0, 65536, 65536,
        nullptr, mask, psum, e_b);

    // rowsum partials -> invl
    inv_kernel<<<256, 256, 0, stream>>>(psum, invl);

    // PV streaming: att fp32 + y bf16
    pv_kernel<<<dim3(16, 64), 256, 0, stream>>>(e_b, vT_bf, invl, att, y_bf);

    // W_o: [4096,1024] x [1024,1024]^T + b_o + x -> x2
    gemm_bt<64, 128, 3><<<dim3(64, 8, 1), 256, 0, stream>>>(
        y_bf, wo_bf, 1024, 1024, 1024, 1024, 0, 0,
        bo, x, x2, nullptr);

    // LN2
    ln_kernel<<<4096, 256, 0, stream>>>(x2, ln2w, ln2b, h_bf);

    // FC + GELU: [4096,1024] x [4096,1024]^T -> gelu_bf [4096,4096]
    gemm_bt<128, 128, 4><<<dim3(32, 32, 1), 256, 0, stream>>>(
        h_bf, wfc_bf, 1024, 1024, 1024, 4096, 0, 0,
        bfc, nullptr, nullptr, gelu_bf);

    // Proj: [4096,4096] x [1024,4096]^T + b_proj + x2 -> out
    gemm_bt<64, 128, 3><<<dim3(64, 8, 1), 256, 0, stream>>>(
        gelu_bf, wproj_bf, 4096, 4096, 4096, 1024, 0, 0,
        bproj, x2, outx, nullptr);
}

// Round 7
// 459.054 us; speedup vs baseline: 1.1218x; 1.1218x over previous
//
#include <hip/hip_runtime.h>
#include <stdint.h>
#include <math.h>

// ---------------- types ----------------
typedef __attribute__((ext_vector_type(4))) float f32x4;
typedef __attribute__((ext_vector_type(8))) short s16x8;   // 8 x bf16 (4 VGPRs)
typedef __attribute__((ext_vector_type(4))) unsigned short u16x4;
typedef __attribute__((ext_vector_type(8))) unsigned short u16x8;

__device__ __forceinline__ unsigned short f2b(float x) {
    union { float f; uint32_t u; } v; v.f = x;
    uint32_t r = v.u + 0x7FFFu + ((v.u >> 16) & 1u);   // round-to-nearest-even
    return (unsigned short)(r >> 16);
}
__device__ __forceinline__ float b2f(unsigned short u) {
    union { uint32_t u; float f; } v; v.u = (uint32_t)u << 16;
    return v.f;
}

__device__ __forceinline__ void gload16(const unsigned short* g, unsigned short* l) {
    __builtin_amdgcn_global_load_lds(
        (const __attribute__((address_space(1))) unsigned int*)(const void*)g,
        (__attribute__((address_space(3))) unsigned int*)(void*)l,
        16, 0, 0);
}

// ---------------- fused fp32 -> bf16 cast of the 4 weight tensors ----------------
__global__ __launch_bounds__(256) void cast4_kernel(
        const float* __restrict__ a, int na, const float* __restrict__ b, int nb,
        const float* __restrict__ c, int nc, const float* __restrict__ d, int nd,
        unsigned short* __restrict__ oa, unsigned short* __restrict__ ob,
        unsigned short* __restrict__ oc, unsigned short* __restrict__ od) {
    int i = blockIdx.x * 256 + threadIdx.x;
    const float* src; unsigned short* dst; int off;
    if (i < na)                { src = a; dst = oa; off = i; }
    else if (i < na+nb)        { src = b; dst = ob; off = i - na; }
    else if (i < na+nb+nc)     { src = c; dst = oc; off = i - na - nb; }
    else if (i < na+nb+nc+nd)  { src = d; dst = od; off = i - na - nb - nc; }
    else return;
    f32x4 v = ((const f32x4*)src)[off];
    u16x4 o;
    #pragma unroll
    for (int j = 0; j < 4; ++j) o[j] = f2b(v[j]);
    ((u16x4*)dst)[off] = o;
}

// ---------------- LayerNorm (C=1024), fp32 in -> bf16 out ----------------
__global__ __launch_bounds__(256) void ln_kernel(const float* __restrict__ x,
                                                 const float* __restrict__ w,
                                                 const float* __restrict__ b,
                                                 unsigned short* __restrict__ out) {
    const long row = blockIdx.x;
    const int tid = threadIdx.x;
    f32x4 v = *(const f32x4*)(x + row * 1024 + tid * 4);
    float s  = v[0] + v[1] + v[2] + v[3];
    float sq = v[0]*v[0] + v[1]*v[1] + v[2]*v[2] + v[3]*v[3];
    #pragma unroll
    for (int off = 32; off; off >>= 1) {
        s  += __shfl_xor(s, off);
        sq += __shfl_xor(sq, off);
    }
    __shared__ float red[8];
    if ((tid & 63) == 0) { red[tid >> 6] = s; red[4 + (tid >> 6)] = sq; }
    __syncthreads();
    s  = red[0] + red[1] + red[2] + red[3];
    sq = red[4] + red[5] + red[6] + red[7];
    float mu  = s * (1.0f / 1024.0f);
    float var = sq * (1.0f / 1024.0f) - mu * mu;
    float rs  = rsqrtf(var + 1e-5f);
    f32x4 wv = *(const f32x4*)(w + tid * 4);
    f32x4 bv = *(const f32x4*)(b + tid * 4);
    u16x4 o;
    #pragma unroll
    for (int j = 0; j < 4; ++j) o[j] = f2b((v[j] - mu) * rs * wv[j] + bv[j]);
    *(u16x4*)(out + row * 1024 + tid * 4) = o;
}

// ---------------- psum[row][16] -> invl[row] = 1/sum ----------------
__global__ __launch_bounds__(256) void inv_kernel(const float* __restrict__ psum,
                                                  float* __restrict__ invl) {
    const long r = blockIdx.x * 256 + threadIdx.x;       // 65536 rows
    const float* p = psum + (r << 4);
    f32x4 a = *(const f32x4*)p,       b = *(const f32x4*)(p + 4);
    f32x4 c = *(const f32x4*)(p + 8), d = *(const f32x4*)(p + 12);
    float s = (a[0]+a[1]+a[2]+a[3]) + (b[0]+b[1]+b[2]+b[3])
            + (c[0]+c[1]+c[2]+c[3]) + (d[0]+d[1]+d[2]+d[3]);
    invl[r] = 1.0f / s;
}

// ---------------- att = E * invl  (streaming, saturating) ----------------
// 2 rows per block: 256 threads x 8 elems = 2048.
__global__ __launch_bounds__(256) void att_kernel(const unsigned short* __restrict__ E,
                                                  const float* __restrict__ invl,
                                                  float* __restrict__ att) {
    const long row = (long)blockIdx.x * 2 + (threadIdx.x >> 7);
    const int col = (threadIdx.x & 127) * 8;
    const float il = invl[row];
    u16x8 e = *(const u16x8*)(E + (row << 10) + col);
    f32x4 o0, o1;
    #pragma unroll
    for (int j = 0; j < 4; ++j) o0[j] = b2f(e[j]) * il;
    #pragma unroll
    for (int j = 0; j < 4; ++j) o1[j] = b2f(e[4 + j]) * il;
    *(f32x4*)(att + (row << 10) + col)     = o0;
    *(f32x4*)(att + (row << 10) + col + 4) = o1;
}

// ---------------- GEMM: C[n,m] = sum_k A[n,k] * B[m,k]  (both row-major over K) --------
// 4-buffer LDS, depth-2 prefetch, counted vmcnt, ONE barrier per K-step (T3+T4-lite).
// EPI: 0=QKV scatter, 1=exp(s+mask)->bf16 E + psum partials, 2=PV *invl -> y scatter,
//      3=bias+resid->f32, 4=bias+GELU->bf16
template <int BM, int BN, int EPI>
__global__ __launch_bounds__(256)
void gemm_bt(const unsigned short* __restrict__ A,
             const unsigned short* __restrict__ Bm,
             int K, int lda, int ldb, int ldc,
             long sAz, long sBz,
             const float* __restrict__ bias,
             const float* __restrict__ resid,
             float* __restrict__ outF,
             unsigned short* __restrict__ outB) {
    constexpr int WM = BM / 2, WN = BN / 2;
    constexpr int FM = WM / 16, FN = WN / 16;
    constexpr int NTA = BM / 64, NTB = BN / 64;
    constexpr int LOADS = NTA + NTB;
    __shared__ unsigned short ldsA[4][BM * 32];
    __shared__ unsigned short ldsB[4][BN * 32];

    const int tid  = threadIdx.x;
    const int lane = tid & 63;
    const int wid  = tid >> 6;
    const int wr   = wid >> 1, wc = wid & 1;
    const int bz   = blockIdx.z;
    const int row0 = blockIdx.x * BM;
    const int col0 = blockIdx.y * BN;

    const unsigned short* Ab = A + (long)bz * sAz + (long)row0 * lda;
    const unsigned short* Bb = Bm + (long)bz * sBz + (long)col0 * ldb;

    const int nt = K >> 5;
    f32x4 acc[FM][FN] = {};
    const int fr = lane & 15;
    const int fk = (lane >> 4) * 8;

    // staging helper (macro to keep gload16 size literal)
#define STAGE(T, BUF)                                                              \
    {                                                                              \
        const int k0s = (T) << 5;                                                  \
        _Pragma("unroll")                                                          \
        for (int i = 0; i < NTA; ++i) {                                            \
            int e = i * 2048 + wid * 512 + lane * 8;                               \
            gload16(Ab + k0s + (long)(e >> 5) * lda + (e & 31),                    \
                    &ldsA[BUF][i * 2048 + wid * 512]);                             \
        }                                                                          \
        _Pragma("unroll")                                                          \
        for (int i = 0; i < NTB; ++i) {                                            \
            int e = i * 2048 + wid * 512 + lane * 8;                               \
            gload16(Bb + k0s + (long)(e >> 5) * ldb + (e & 31),                    \
                    &ldsB[BUF][i * 2048 + wid * 512]);                             \
        }                                                                          \
    }

    // prologue: stage tiles 0 and 1
    STAGE(0, 0);
    if (nt > 1) STAGE(1, 1);

    for (int t = 0; t < nt; ++t) {
        const int buf = t & 3;
        if (t + 2 < nt) {
            STAGE(t + 2, (t + 2) & 3);
            // wait: tiles t+1, t+2 in flight (2*LOADS), tile t landed
            if constexpr (LOADS == 2)      asm volatile("s_waitcnt vmcnt(4)" ::: "memory");
            else if constexpr (LOADS == 3) asm volatile("s_waitcnt vmcnt(6)" ::: "memory");
            else                           asm volatile("s_waitcnt vmcnt(8)" ::: "memory");
        } else if (t + 1 < nt) {
            if constexpr (LOADS == 2)      asm volatile("s_waitcnt vmcnt(2)" ::: "memory");
            else if constexpr (LOADS == 3) asm volatile("s_waitcnt vmcnt(3)" ::: "memory");
            else                           asm volatile("s_waitcnt vmcnt(4)" ::: "memory");
        } else {
            asm volatile("s_waitcnt vmcnt(0)" ::: "memory");
        }
        __syncthreads();

        s16x8 af[FM], bfr[FN];
        #pragma unroll
        for (int m = 0; m < FM; ++m)
            af[m] = *(const s16x8*)&ldsA[buf][(wr * WM + m * 16 + fr) * 32 + fk];
        #pragma unroll
        for (int n = 0; n < FN; ++n)
            bfr[n] = *(const s16x8*)&ldsB[buf][(wc * WN + n * 16 + fr) * 32 + fk];
        #pragma unroll
        for (int m = 0; m < FM; ++m)
            #pragma unroll
            for (int n = 0; n < FN; ++n)
                acc[m][n] = __builtin_amdgcn_mfma_f32_16x16x32_bf16(af[m], bfr[n], acc[m][n], 0, 0, 0);
    }
#undef STAGE

    // epilogue: D mapping col=lane&15, row=(lane>>4)*4+reg  [m89-verified]
    const int cj = lane & 15;
    const int r0 = (lane >> 4) * 4;

    if constexpr (EPI == 1) {
        // exp(s + mask) -> bf16 E, plus per-(block,wave) partial row sums (no atomics)
        #pragma unroll
        for (int m = 0; m < FM; ++m) {
            #pragma unroll
            for (int r = 0; r < 4; ++r) {
                const int grow = row0 + wr * WM + m * 16 + r0 + r;   // q-row in [0,1024)
                float rs = 0.0f;
                #pragma unroll
                for (int n = 0; n < FN; ++n) {
                    const int gcol = col0 + wc * WN + n * 16 + cj;
                    float e = __expf(acc[m][n][r] + resid[((long)grow << 10) + gcol]);
                    rs += e;
                    outB[((long)bz << 20) + ((long)grow << 10) + gcol] = f2b(e);
                }
                rs += __shfl_xor(rs, 1); rs += __shfl_xor(rs, 2);
                rs += __shfl_xor(rs, 4); rs += __shfl_xor(rs, 8);
                if (cj == 0)
                    outF[((((long)bz << 10) + grow) << 4) + blockIdx.y * 2 + wc] = rs;
            }
        }
    } else {
        #pragma unroll
        for (int m = 0; m < FM; ++m) {
            #pragma unroll
            for (int n = 0; n < FN; ++n) {
                #pragma unroll
                for (int r = 0; r < 4; ++r) {
                    const int grow = row0 + wr * WM + m * 16 + r0 + r;
                    const int gcol = col0 + wc * WN + n * 16 + cj;
                    float v = acc[m][n][r];
                    if constexpr (EPI == 0) {
                        // QKV scatter: q*0.125 -> [BH,T,64]; k -> [BH,T,64]; v -> vT [BH,64,T]
                        v += bias[gcol];
                        const int bb = grow >> 10, t = grow & 1023;
                        const int seg = gcol >> 10, mm = gcol & 1023;
                        const int hh = mm >> 6, dd = mm & 63;
                        const long bh = bb * 16 + hh;
                        if (seg == 0)
                            outB[(bh << 16) + (t << 6) + dd] = f2b(v * 0.125f);
                        else if (seg == 1)
                            outB[4194304 + (bh << 16) + (t << 6) + dd] = f2b(v);
                        else
                            outB[8388608 + (bh << 16) + (dd << 10) + t] = f2b(v);
                    } else if constexpr (EPI == 2) {
                        // PV: scale by invl (per q-row), scatter to y [B,T,C]
                        const float il = bias[((long)bz << 10) + grow];
                        const int bb = bz >> 4, hh = bz & 15;
                        outB[((long)((bb << 10) | grow) << 10) + (hh << 6) + gcol] =
                            f2b(v * il);
                    } else if constexpr (EPI == 3) {
                        const long idx = ((long)grow << 10) + gcol;   // out row stride 1024
                        outF[idx] = v + bias[gcol] + resid[idx];
                    } else if constexpr (EPI == 4) {
                        float u = v + bias[gcol];
                        float g = 0.5f * u * (1.0f + erff(u * 0.70710678118f));
                        outB[(long)grow * ldc + gcol] = f2b(g);
                    }
                }
            }
        }
    }
}

// ---------------- launch ----------------
extern "C" void kernel_launch(void* const* d_in, const int* in_sizes, int n_in,
                              void* d_out, int out_size, void* d_ws, size_t ws_size,
                              hipStream_t stream) {
    (void)in_sizes; (void)n_in; (void)out_size; (void)ws_size;
    const float* x     = (const float*)d_in[0];
    const float* mask  = (const float*)d_in[1];
    const float* ln1w  = (const float*)d_in[2];
    const float* ln1b  = (const float*)d_in[3];
    const float* wqkv  = (const float*)d_in[4];
    const float* bqkv  = (const float*)d_in[5];
    const float* wo    = (const float*)d_in[6];
    const float* bo    = (const float*)d_in[7];
    const float* ln2w  = (const float*)d_in[8];
    const float* ln2b  = (const float*)d_in[9];
    const float* wfc   = (const float*)d_in[10];
    const float* bfc   = (const float*)d_in[11];
    const float* wproj = (const float*)d_in[12];
    const float* bproj = (const float*)d_in[13];

    float* outx = (float*)d_out;                     // [4096,1024] fp32
    float* att  = (float*)d_out + 4194304;           // [64,1024,1024] fp32

    char* ws = (char*)d_ws;
    unsigned short* h_bf     = (unsigned short*)ws;  ws += (size_t)8  << 20;  // [4096,1024]
    unsigned short* wqkv_bf  = (unsigned short*)ws;  ws += (size_t)6  << 20;  // [3072,1024]
    unsigned short* wo_bf    = (unsigned short*)ws;  ws += (size_t)2  << 20;  // [1024,1024]
    unsigned short* wfc_bf   = (unsigned short*)ws;  ws += (size_t)8  << 20;  // [4096,1024]
    unsigned short* wproj_bf = (unsigned short*)ws;  ws += (size_t)8  << 20;  // [1024,4096]
    unsigned short* q_bf     = (unsigned short*)ws;  ws += (size_t)24 << 20;  // q,k,vT contiguous
    unsigned short* k_bf     = q_bf + 4194304;
    unsigned short* vT_bf    = q_bf + 8388608;
    unsigned short* e_b      = (unsigned short*)ws;  ws += (size_t)128 << 20; // [64,1024,1024] bf16 exp
    unsigned short* y_bf     = (unsigned short*)ws;  ws += (size_t)8  << 20;  // [4096,1024]
    float*          x2       = (float*)ws;           ws += (size_t)16 << 20;  // [4096,1024] f32
    unsigned short* gelu_bf  = (unsigned short*)ws;  ws += (size_t)32 << 20;  // [4096,4096]
    float*          psum     = (float*)ws;           ws += (size_t)4  << 20;  // [64,1024,16] f32
    float*          invl     = (float*)ws;           ws += (size_t)256 << 10; // [64,1024] f32

    // weights -> bf16 (single fused launch)
    cast4_kernel<<<12288, 256, 0, stream>>>(
        wqkv, 786432, wo, 262144, wfc, 1048576, wproj, 1048576,
        wqkv_bf, wo_bf, wfc_bf, wproj_bf);

    // LN1
    ln_kernel<<<4096, 256, 0, stream>>>(x, ln1w, ln1b, h_bf);

    // QKV: [4096,1024] x [3072,1024]^T -> q(scaled)/k/vT scatter
    gemm_bt<128, 128, 0><<<dim3(32, 24, 1), 256, 0, stream>>>(
        h_bf, wqkv_bf, 1024, 1024, 1024, 0, 0, 0,
        bqkv, nullptr, nullptr, q_bf);

    // scores: per (b,h): [1024,64] x [1024,64]^T -> E = exp(s+mask) bf16 + psum
    gemm_bt<128, 128, 1><<<dim3(8, 8, 64), 256, 0, stream>>>(
        q_bf, k_bf, 64, 64, 64, 0, 65536, 65536,
        nullptr, mask, psum, e_b);

    // rowsum partials -> invl
    inv_kernel<<<256, 256, 0, stream>>>(psum, invl);

    // att = E * invl (fp32, output 1)
    att_kernel<<<32768, 256, 0, stream>>>(e_b, invl, att);

    // PV: per (b,h): [1024,1024](E) x [64,1024](vT)^T -> y, scaled by invl
    gemm_bt<128, 64, 2><<<dim3(8, 1, 64), 256, 0, stream>>>(
        e_b, vT_bf, 1024, 1024, 1024, 0, 1048576, 65536,
        invl, nullptr, nullptr, y_bf);

    // W_o: [4096,1024] x [1024,1024]^T + b_o + x -> x2
    gemm_bt<64, 128, 3><<<dim3(64, 8, 1), 256, 0, stream>>>(
        y_bf, wo_bf, 1024, 1024, 1024, 1024, 0, 0,
        bo, x, x2, nullptr);

    // LN2
    ln_kernel<<<4096, 256, 0, stream>>>(x2, ln2w, ln2b, h_bf);

    // FC + GELU: [4096,1024] x [4096,1024]^T -> gelu_bf [4096,4096]
    gemm_bt<128, 128, 4><<<dim3(32, 32, 1), 256, 0, stream>>>(
        h_bf, wfc_bf, 1024, 1024, 1024, 4096, 0, 0,
        bfc, nullptr, nullptr, gelu_bf);

    // Proj: [4096,4096] x [1024,4096]^T + b_proj + x2 -> out
    gemm_bt<64, 128, 3><<<dim3(64, 8, 1), 256, 0, stream>>>(
        gelu_bf, wproj_bf, 4096, 4096, 4096, 1024, 0, 0,
        bproj, x2, outx, nullptr);
}

// Round 8
// 448.884 us; speedup vs baseline: 1.1472x; 1.0227x over previous
//
#include <hip/hip_runtime.h>
#include <stdint.h>
#include <math.h>

// ---------------- types ----------------
typedef __attribute__((ext_vector_type(4))) float f32x4;
typedef __attribute__((ext_vector_type(8))) short s16x8;   // 8 x bf16 (4 VGPRs)
typedef __attribute__((ext_vector_type(4))) unsigned short u16x4;
typedef __attribute__((ext_vector_type(8))) unsigned short u16x8;

__device__ __forceinline__ unsigned short f2b(float x) {
    union { float f; uint32_t u; } v; v.f = x;
    uint32_t r = v.u + 0x7FFFu + ((v.u >> 16) & 1u);   // round-to-nearest-even
    return (unsigned short)(r >> 16);
}
__device__ __forceinline__ float b2f(unsigned short u) {
    union { uint32_t u; float f; } v; v.u = (uint32_t)u << 16;
    return v.f;
}

__device__ __forceinline__ void gload16(const unsigned short* g, unsigned short* l) {
    __builtin_amdgcn_global_load_lds(
        (const __attribute__((address_space(1))) unsigned int*)(const void*)g,
        (__attribute__((address_space(3))) unsigned int*)(void*)l,
        16, 0, 0);
}

// ---------------- fused fp32 -> bf16 cast of the 4 weight tensors ----------------
__global__ __launch_bounds__(256) void cast4_kernel(
        const float* __restrict__ a, int na, const float* __restrict__ b, int nb,
        const float* __restrict__ c, int nc, const float* __restrict__ d, int nd,
        unsigned short* __restrict__ oa, unsigned short* __restrict__ ob,
        unsigned short* __restrict__ oc, unsigned short* __restrict__ od) {
    int i = blockIdx.x * 256 + threadIdx.x;
    const float* src; unsigned short* dst; int off;
    if (i < na)                { src = a; dst = oa; off = i; }
    else if (i < na+nb)        { src = b; dst = ob; off = i - na; }
    else if (i < na+nb+nc)     { src = c; dst = oc; off = i - na - nb; }
    else if (i < na+nb+nc+nd)  { src = d; dst = od; off = i - na - nb - nc; }
    else return;
    f32x4 v = ((const f32x4*)src)[off];
    u16x4 o;
    #pragma unroll
    for (int j = 0; j < 4; ++j) o[j] = f2b(v[j]);
    ((u16x4*)dst)[off] = o;
}

// ---------------- LayerNorm (C=1024), fp32 in -> bf16 out ----------------
__global__ __launch_bounds__(256) void ln_kernel(const float* __restrict__ x,
                                                 const float* __restrict__ w,
                                                 const float* __restrict__ b,
                                                 unsigned short* __restrict__ out) {
    const long row = blockIdx.x;
    const int tid = threadIdx.x;
    f32x4 v = *(const f32x4*)(x + row * 1024 + tid * 4);
    float s  = v[0] + v[1] + v[2] + v[3];
    float sq = v[0]*v[0] + v[1]*v[1] + v[2]*v[2] + v[3]*v[3];
    #pragma unroll
    for (int off = 32; off; off >>= 1) {
        s  += __shfl_xor(s, off);
        sq += __shfl_xor(sq, off);
    }
    __shared__ float red[8];
    if ((tid & 63) == 0) { red[tid >> 6] = s; red[4 + (tid >> 6)] = sq; }
    __syncthreads();
    s  = red[0] + red[1] + red[2] + red[3];
    sq = red[4] + red[5] + red[6] + red[7];
    float mu  = s * (1.0f / 1024.0f);
    float var = sq * (1.0f / 1024.0f) - mu * mu;
    float rs  = rsqrtf(var + 1e-5f);
    f32x4 wv = *(const f32x4*)(w + tid * 4);
    f32x4 bv = *(const f32x4*)(b + tid * 4);
    u16x4 o;
    #pragma unroll
    for (int j = 0; j < 4; ++j) o[j] = f2b((v[j] - mu) * rs * wv[j] + bv[j]);
    *(u16x4*)(out + row * 1024 + tid * 4) = o;
}

// ---------------- psum[row][16] -> invl[row] = 1/sum ----------------
__global__ __launch_bounds__(256) void inv_kernel(const float* __restrict__ psum,
                                                  float* __restrict__ invl) {
    const long r = blockIdx.x * 256 + threadIdx.x;       // 65536 rows
    const float* p = psum + (r << 4);
    f32x4 a = *(const f32x4*)p,       b = *(const f32x4*)(p + 4);
    f32x4 c = *(const f32x4*)(p + 8), d = *(const f32x4*)(p + 12);
    float s = (a[0]+a[1]+a[2]+a[3]) + (b[0]+b[1]+b[2]+b[3])
            + (c[0]+c[1]+c[2]+c[3]) + (d[0]+d[1]+d[2]+d[3]);
    invl[r] = 1.0f / s;
}

// ---------------- fused PV + att-write ----------------
// block: 64 q-rows x 64 d, one bh. K=1024 over E columns, BK=32, 3 LDS bufs,
// stage-after-barrier, counted vmcnt (stores included in the count).
// In-loop: att[q,k] = E*invl (fp32) written from the staged LDS tile.
__global__ __launch_bounds__(256)
void pv_att(const unsigned short* __restrict__ E,    // [64][1024][1024] bf16 exp
            const unsigned short* __restrict__ Vt,   // [64][64][1024] bf16 (d-major)
            const float* __restrict__ invl,          // [64][1024]
            float* __restrict__ att,                 // [64][1024][1024] fp32
            unsigned short* __restrict__ y) {        // [4096][1024] bf16 scatter
    __shared__ unsigned short ldsA[3][64 * 32];
    __shared__ unsigned short ldsB[3][64 * 32];
    const int tid = threadIdx.x, lane = tid & 63, wid = tid >> 6;
    const int wr = wid >> 1, wc = wid & 1;
    const int bh = blockIdx.y;
    const int q0 = blockIdx.x * 64;
    const int fr = lane & 15, fs = lane >> 4;

    const unsigned short* Ab = E + ((long)bh << 20) + (long)q0 * 1024;
    const unsigned short* Bb = Vt + ((long)bh << 16);

    const int e0  = wid * 512 + lane * 8;
    const int r0a = e0 >> 5, c0a = e0 & 31;      // this thread's staged row/col
    const float il_a = invl[(bh << 10) + q0 + r0a];
    float* attRow = att + ((long)bh << 20) + (long)(q0 + r0a) * 1024 + c0a;

    f32x4 acc[2][2] = {};

#define PSTAGE(T, BUF)                                                        \
    {                                                                         \
        const int k0s = (T) << 5;                                             \
        gload16(Ab + k0s + (long)r0a * 1024 + c0a, &ldsA[BUF][wid * 512]);    \
        gload16(Bb + k0s + (long)r0a * 1024 + c0a, &ldsB[BUF][wid * 512]);    \
    }

    PSTAGE(0, 0);
    PSTAGE(1, 1);

    for (int t = 0; t < 32; ++t) {
        const int buf = t % 3;
        asm volatile("s_waitcnt vmcnt(4)" ::: "memory");
        __syncthreads();
        if (t + 2 < 32) PSTAGE(t + 2, (t + 2) % 3);

        // att write from staged tile (own 8 elems)
        {
            s16x8 ea = *(const s16x8*)&ldsA[buf][e0];
            f32x4 o0, o1;
            #pragma unroll
            for (int j = 0; j < 4; ++j) o0[j] = b2f((unsigned short)ea[j]) * il_a;
            #pragma unroll
            for (int j = 0; j < 4; ++j) o1[j] = b2f((unsigned short)ea[4 + j]) * il_a;
            *(f32x4*)(attRow + t * 32)     = o0;
            *(f32x4*)(attRow + t * 32 + 4) = o1;
        }

        s16x8 af[2], vb[2];
        #pragma unroll
        for (int m = 0; m < 2; ++m)
            af[m] = *(const s16x8*)&ldsA[buf][(wr * 32 + m * 16 + fr) * 32 + fs * 8];
        #pragma unroll
        for (int n = 0; n < 2; ++n)
            vb[n] = *(const s16x8*)&ldsB[buf][(wc * 32 + n * 16 + fr) * 32 + fs * 8];
        #pragma unroll
        for (int m = 0; m < 2; ++m)
            #pragma unroll
            for (int n = 0; n < 2; ++n)
                acc[m][n] = __builtin_amdgcn_mfma_f32_16x16x32_bf16(af[m], vb[n], acc[m][n], 0, 0, 0);
    }
#undef PSTAGE

    // y scatter: [B,T,C] bf16, scaled by invl of the output row
    const int bb = bh >> 4, hh = bh & 15;
    #pragma unroll
    for (int m = 0; m < 2; ++m) {
        #pragma unroll
        for (int r = 0; r < 4; ++r) {
            const int trow = q0 + wr * 32 + m * 16 + fs * 4 + r;
            const float il = invl[(bh << 10) + trow];
            #pragma unroll
            for (int n = 0; n < 2; ++n) {
                const int c = hh * 64 + wc * 32 + n * 16 + fr;
                y[((long)(bb * 1024 + trow) << 10) + c] = f2b(acc[m][n][r] * il);
            }
        }
    }
}

// ---------------- GEMM: C[n,m] = sum_k A[n,k] * B[m,k]  (both row-major over K) --------
// 3-buffer LDS, stage-after-barrier, depth-2 prefetch, counted vmcnt, 1 barrier/K-step.
// EPI: 0=QKV scatter, 1=exp(s+mask)->bf16 E + psum partials, 3=bias+resid->f32, 4=bias+GELU->bf16
template <int BM, int BN, int EPI>
__global__ __launch_bounds__(256)
void gemm_bt(const unsigned short* __restrict__ A,
             const unsigned short* __restrict__ Bm,
             int K, int lda, int ldb, int ldc,
             long sAz, long sBz,
             const float* __restrict__ bias,
             const float* __restrict__ resid,
             float* __restrict__ outF,
             unsigned short* __restrict__ outB) {
    constexpr int WM = BM / 2, WN = BN / 2;
    constexpr int FM = WM / 16, FN = WN / 16;
    constexpr int NTA = BM / 64, NTB = BN / 64;
    constexpr int LOADS = NTA + NTB;
    __shared__ unsigned short ldsA[3][BM * 32];
    __shared__ unsigned short ldsB[3][BN * 32];

    const int tid  = threadIdx.x;
    const int lane = tid & 63;
    const int wid  = tid >> 6;
    const int wr   = wid >> 1, wc = wid & 1;
    const int bz   = blockIdx.z;
    const int row0 = blockIdx.x * BM;
    const int col0 = blockIdx.y * BN;

    const unsigned short* Ab = A + (long)bz * sAz + (long)row0 * lda;
    const unsigned short* Bb = Bm + (long)bz * sBz + (long)col0 * ldb;

    const int nt = K >> 5;
    f32x4 acc[FM][FN] = {};
    const int fr = lane & 15;
    const int fk = (lane >> 4) * 8;

#define STAGE(T, BUF)                                                              \
    {                                                                              \
        const int k0s = (T) << 5;                                                  \
        _Pragma("unroll")                                                          \
        for (int i = 0; i < NTA; ++i) {                                            \
            int e = i * 2048 + wid * 512 + lane * 8;                               \
            gload16(Ab + k0s + (long)(e >> 5) * lda + (e & 31),                    \
                    &ldsA[BUF][i * 2048 + wid * 512]);                             \
        }                                                                          \
        _Pragma("unroll")                                                          \
        for (int i = 0; i < NTB; ++i) {                                            \
            int e = i * 2048 + wid * 512 + lane * 8;                               \
            gload16(Bb + k0s + (long)(e >> 5) * ldb + (e & 31),                    \
                    &ldsB[BUF][i * 2048 + wid * 512]);                             \
        }                                                                          \
    }

    STAGE(0, 0);
    if (nt > 1) STAGE(1, 1);

    for (int t = 0; t < nt; ++t) {
        const int buf = t % 3;
        if (t + 1 < nt) {
            if constexpr (LOADS == 2)      asm volatile("s_waitcnt vmcnt(2)" ::: "memory");
            else if constexpr (LOADS == 3) asm volatile("s_waitcnt vmcnt(3)" ::: "memory");
            else                           asm volatile("s_waitcnt vmcnt(4)" ::: "memory");
        } else {
            asm volatile("s_waitcnt vmcnt(0)" ::: "memory");
        }
        __syncthreads();
        if (t + 2 < nt) STAGE(t + 2, (t + 2) % 3);

        s16x8 af[FM], bfr[FN];
        #pragma unroll
        for (int m = 0; m < FM; ++m)
            af[m] = *(const s16x8*)&ldsA[buf][(wr * WM + m * 16 + fr) * 32 + fk];
        #pragma unroll
        for (int n = 0; n < FN; ++n)
            bfr[n] = *(const s16x8*)&ldsB[buf][(wc * WN + n * 16 + fr) * 32 + fk];
        #pragma unroll
        for (int m = 0; m < FM; ++m)
            #pragma unroll
            for (int n = 0; n < FN; ++n)
                acc[m][n] = __builtin_amdgcn_mfma_f32_16x16x32_bf16(af[m], bfr[n], acc[m][n], 0, 0, 0);
    }
#undef STAGE

    // epilogue: D mapping col=lane&15, row=(lane>>4)*4+reg  [m89-verified]
    const int cj = lane & 15;
    const int r0 = (lane >> 4) * 4;

    if constexpr (EPI == 1) {
        // exp(s + mask) -> bf16 E, plus per-(block,wave) partial row sums (no atomics)
        #pragma unroll
        for (int m = 0; m < FM; ++m) {
            #pragma unroll
            for (int r = 0; r < 4; ++r) {
                const int grow = row0 + wr * WM + m * 16 + r0 + r;   // q-row in [0,1024)
                float rs = 0.0f;
                #pragma unroll
                for (int n = 0; n < FN; ++n) {
                    const int gcol = col0 + wc * WN + n * 16 + cj;
                    float e = __expf(acc[m][n][r] + resid[((long)grow << 10) + gcol]);
                    rs += e;
                    outB[((long)bz << 20) + ((long)grow << 10) + gcol] = f2b(e);
                }
                rs += __shfl_xor(rs, 1); rs += __shfl_xor(rs, 2);
                rs += __shfl_xor(rs, 4); rs += __shfl_xor(rs, 8);
                if (cj == 0)
                    outF[((((long)bz << 10) + grow) << 4) + blockIdx.y * 2 + wc] = rs;
            }
        }
    } else {
        #pragma unroll
        for (int m = 0; m < FM; ++m) {
            #pragma unroll
            for (int n = 0; n < FN; ++n) {
                #pragma unroll
                for (int r = 0; r < 4; ++r) {
                    const int grow = row0 + wr * WM + m * 16 + r0 + r;
                    const int gcol = col0 + wc * WN + n * 16 + cj;
                    float v = acc[m][n][r];
                    if constexpr (EPI == 0) {
                        // QKV scatter: q*0.125 -> [BH,T,64]; k -> [BH,T,64]; v -> vT [BH,64,T]
                        v += bias[gcol];
                        const int bb = grow >> 10, t = grow & 1023;
                        const int seg = gcol >> 10, mm = gcol & 1023;
                        const int hh = mm >> 6, dd = mm & 63;
                        const long bh = bb * 16 + hh;
                        if (seg == 0)
                            outB[(bh << 16) + (t << 6) + dd] = f2b(v * 0.125f);
                        else if (seg == 1)
                            outB[4194304 + (bh << 16) + (t << 6) + dd] = f2b(v);
                        else
                            outB[8388608 + (bh << 16) + (dd << 10) + t] = f2b(v);
                    } else if constexpr (EPI == 3) {
                        const long idx = ((long)grow << 10) + gcol;   // out row stride 1024
                        outF[idx] = v + bias[gcol] + resid[idx];
                    } else if constexpr (EPI == 4) {
                        float u = v + bias[gcol];
                        float g = 0.5f * u * (1.0f + erff(u * 0.70710678118f));
                        outB[(long)grow * ldc + gcol] = f2b(g);
                    }
                }
            }
        }
    }
}

// ---------------- launch ----------------
extern "C" void kernel_launch(void* const* d_in, const int* in_sizes, int n_in,
                              void* d_out, int out_size, void* d_ws, size_t ws_size,
                              hipStream_t stream) {
    (void)in_sizes; (void)n_in; (void)out_size; (void)ws_size;
    const float* x     = (const float*)d_in[0];
    const float* mask  = (const float*)d_in[1];
    const float* ln1w  = (const float*)d_in[2];
    const float* ln1b  = (const float*)d_in[3];
    const float* wqkv  = (const float*)d_in[4];
    const float* bqkv  = (const float*)d_in[5];
    const float* wo    = (const float*)d_in[6];
    const float* bo    = (const float*)d_in[7];
    const float* ln2w  = (const float*)d_in[8];
    const float* ln2b  = (const float*)d_in[9];
    const float* wfc   = (const float*)d_in[10];
    const float* bfc   = (const float*)d_in[11];
    const float* wproj = (const float*)d_in[12];
    const float* bproj = (const float*)d_in[13];

    float* outx = (float*)d_out;                     // [4096,1024] fp32
    float* att  = (float*)d_out + 4194304;           // [64,1024,1024] fp32

    char* ws = (char*)d_ws;
    unsigned short* h_bf     = (unsigned short*)ws;  ws += (size_t)8  << 20;  // [4096,1024]
    unsigned short* wqkv_bf  = (unsigned short*)ws;  ws += (size_t)6  << 20;  // [3072,1024]
    unsigned short* wo_bf    = (unsigned short*)ws;  ws += (size_t)2  << 20;  // [1024,1024]
    unsigned short* wfc_bf   = (unsigned short*)ws;  ws += (size_t)8  << 20;  // [4096,1024]
    unsigned short* wproj_bf = (unsigned short*)ws;  ws += (size_t)8  << 20;  // [1024,4096]
    unsigned short* q_bf     = (unsigned short*)ws;  ws += (size_t)24 << 20;  // q,k,vT contiguous
    unsigned short* k_bf     = q_bf + 4194304;
    unsigned short* vT_bf    = q_bf + 8388608;
    unsigned short* e_b      = (unsigned short*)ws;  ws += (size_t)128 << 20; // [64,1024,1024] bf16 exp
    unsigned short* y_bf     = (unsigned short*)ws;  ws += (size_t)8  << 20;  // [4096,1024]
    float*          x2       = (float*)ws;           ws += (size_t)16 << 20;  // [4096,1024] f32
    unsigned short* gelu_bf  = (unsigned short*)ws;  ws += (size_t)32 << 20;  // [4096,4096]
    float*          psum     = (float*)ws;           ws += (size_t)4  << 20;  // [64,1024,16] f32
    float*          invl     = (float*)ws;           ws += (size_t)256 << 10; // [64,1024] f32

    // weights -> bf16 (single fused launch)
    cast4_kernel<<<12288, 256, 0, stream>>>(
        wqkv, 786432, wo, 262144, wfc, 1048576, wproj, 1048576,
        wqkv_bf, wo_bf, wfc_bf, wproj_bf);

    // LN1
    ln_kernel<<<4096, 256, 0, stream>>>(x, ln1w, ln1b, h_bf);

    // QKV: [4096,1024] x [3072,1024]^T -> q(scaled)/k/vT scatter
    gemm_bt<128, 128, 0><<<dim3(32, 24, 1), 256, 0, stream>>>(
        h_bf, wqkv_bf, 1024, 1024, 1024, 0, 0, 0,
        bqkv, nullptr, nullptr, q_bf);

    // scores: per (b,h): [1024,64] x [1024,64]^T -> E = exp(s+mask) bf16 + psum
    gemm_bt<128, 128, 1><<<dim3(8, 8, 64), 256, 0, stream>>>(
        q_bf, k_bf, 64, 64, 64, 0, 65536, 65536,
        nullptr, mask, psum, e_b);

    // rowsum partials -> invl
    inv_kernel<<<256, 256, 0, stream>>>(psum, invl);

    // fused PV + att write
    pv_att<<<dim3(16, 64), 256, 0, stream>>>(e_b, vT_bf, invl, att, y_bf);

    // W_o: [4096,1024] x [1024,1024]^T + b_o + x -> x2
    gemm_bt<64, 128, 3><<<dim3(64, 8, 1), 256, 0, stream>>>(
        y_bf, wo_bf, 1024, 1024, 1024, 1024, 0, 0,
        bo, x, x2, nullptr);

    // LN2
    ln_kernel<<<4096, 256, 0, stream>>>(x2, ln2w, ln2b, h_bf);

    // FC + GELU: [4096,1024] x [4096,1024]^T -> gelu_bf [4096,4096]
    gemm_bt<128, 128, 4><<<dim3(32, 32, 1), 256, 0, stream>>>(
        h_bf, wfc_bf, 1024, 1024, 1024, 4096, 0, 0,
        bfc, nullptr, nullptr, gelu_bf);

    // Proj: [4096,4096] x [1024,4096]^T + b_proj + x2 -> out
    gemm_bt<64, 128, 3><<<dim3(64, 8, 1), 256, 0, stream>>>(
        gelu_bf, wproj_bf, 4096, 4096, 4096, 1024, 0, 0,
        bproj, x2, outx, nullptr);
}